// Round 1
// baseline (922.394 us; speedup 1.0000x reference)
//
#include <hip/hip_runtime.h>

#define NROWS   16384   // B*T
#define INDIM   1024
#define KDIM    256     // latent
#define NCODES  4096
#define ROWS    64      // rows per block
#define CT      64      // codes per LDS tile
#define STR     260     // LDS row stride (floats): mult of 4 (b128 align), 260%32=4 -> <=2-way conflicts

// ---------------- cnorm[c] = sum_k cb[c][k]^2 ----------------
__global__ __launch_bounds__(256) void cnorm_kernel(const float* __restrict__ cb,
                                                    float* __restrict__ cnorm) {
    int c    = blockIdx.x * 4 + (threadIdx.x >> 6);
    int lane = threadIdx.x & 63;
    float4 v = ((const float4*)(cb + (size_t)c * KDIM))[lane];
    float s = v.x * v.x + v.y * v.y + v.z * v.z + v.w * v.w;
    #pragma unroll
    for (int off = 1; off < 64; off <<= 1) s += __shfl_xor(s, off);
    if (lane == 0) cnorm[c] = s;
}

// ---------------- fused: h = x@W+b ; argmin dist ; gather ----------------
__global__ __launch_bounds__(256, 1) void vq_kernel(
    const float* __restrict__ x,      // [NROWS][INDIM]
    const float* __restrict__ W,      // [INDIM][KDIM]
    const float* __restrict__ bvec,   // [KDIM]
    const float* __restrict__ cb,     // [NCODES][KDIM]
    const float* __restrict__ cnorm,  // [NCODES]
    float* __restrict__ codes_out,    // [NROWS][KDIM]
    float* __restrict__ idx_out)      // [NROWS] (written as float)
{
    __shared__ float h_lds[ROWS * STR];
    __shared__ float cb_lds[CT * STR];

    const int t  = threadIdx.x;
    const int cg = t & 15;    // 0..15
    const int rg = t >> 4;    // 0..15
    const size_t n0 = (size_t)blockIdx.x * ROWS;

    // ---------------- Phase 1: h[64][256] = x@W + b ----------------
    // thread owns rows rg+16j (j=0..3), cols cg*16 .. cg*16+15
    {
        const int c0 = cg * 16;
        float acc[4][16];
        #pragma unroll
        for (int j = 0; j < 4; ++j)
            #pragma unroll
            for (int cc = 0; cc < 16; ++cc) acc[j][cc] = 0.f;

        for (int k4 = 0; k4 < INDIM / 4; ++k4) {
            const int k = k4 * 4;
            float4 xv[4];
            #pragma unroll
            for (int j = 0; j < 4; ++j)
                xv[j] = *(const float4*)(x + (n0 + rg + 16 * j) * INDIM + k);
            float4 wv[4][4];  // [kk][quad of 4 cols]
            #pragma unroll
            for (int kk = 0; kk < 4; ++kk)
                #pragma unroll
                for (int q = 0; q < 4; ++q)
                    wv[kk][q] = *(const float4*)(W + (size_t)(k + kk) * KDIM + c0 + 4 * q);
            #pragma unroll
            for (int j = 0; j < 4; ++j) {
                const float xs[4] = {xv[j].x, xv[j].y, xv[j].z, xv[j].w};
                #pragma unroll
                for (int kk = 0; kk < 4; ++kk) {
                    #pragma unroll
                    for (int q = 0; q < 4; ++q) {
                        acc[j][4 * q + 0] = fmaf(xs[kk], wv[kk][q].x, acc[j][4 * q + 0]);
                        acc[j][4 * q + 1] = fmaf(xs[kk], wv[kk][q].y, acc[j][4 * q + 1]);
                        acc[j][4 * q + 2] = fmaf(xs[kk], wv[kk][q].z, acc[j][4 * q + 2]);
                        acc[j][4 * q + 3] = fmaf(xs[kk], wv[kk][q].w, acc[j][4 * q + 3]);
                    }
                }
            }
        }
        // + bias, store to LDS
        #pragma unroll
        for (int j = 0; j < 4; ++j) {
            const int r = rg + 16 * j;
            #pragma unroll
            for (int q = 0; q < 4; ++q) {
                float4 v;
                v.x = acc[j][4 * q + 0] + bvec[c0 + 4 * q + 0];
                v.y = acc[j][4 * q + 1] + bvec[c0 + 4 * q + 1];
                v.z = acc[j][4 * q + 2] + bvec[c0 + 4 * q + 2];
                v.w = acc[j][4 * q + 3] + bvec[c0 + 4 * q + 3];
                *(float4*)&h_lds[r * STR + c0 + 4 * q] = v;
            }
        }
    }
    __syncthreads();

    // ---------------- Phase 2: distances + running argmin ----------------
    float minv[4];
    int   mini[4];
    #pragma unroll
    for (int j = 0; j < 4; ++j) { minv[j] = 3.4e38f; mini[j] = 0; }

    for (int ct = 0; ct < NCODES / CT; ++ct) {
        // load codebook tile [CT][KDIM] into LDS (coalesced)
        #pragma unroll
        for (int it = 0; it < (CT * KDIM / 4) / 256; ++it) {
            const int i = t + 256 * it;
            const int c = i >> 6;         // /(KDIM/4)
            const int q = i & 63;
            float4 v = ((const float4*)(cb + ((size_t)(ct * CT + c)) * KDIM))[q];
            *(float4*)&cb_lds[c * STR + 4 * q] = v;
        }
        __syncthreads();

        float acc[4][4];
        #pragma unroll
        for (int j = 0; j < 4; ++j)
            #pragma unroll
            for (int i = 0; i < 4; ++i) acc[j][i] = 0.f;

        #pragma unroll 2
        for (int k4 = 0; k4 < KDIM / 4; ++k4) {
            float4 hv[4], cv[4];
            #pragma unroll
            for (int j = 0; j < 4; ++j)
                hv[j] = *(const float4*)&h_lds[(rg + 16 * j) * STR + 4 * k4];
            #pragma unroll
            for (int i = 0; i < 4; ++i)
                cv[i] = *(const float4*)&cb_lds[(cg + 16 * i) * STR + 4 * k4];
            #pragma unroll
            for (int j = 0; j < 4; ++j)
                #pragma unroll
                for (int i = 0; i < 4; ++i) {
                    acc[j][i] = fmaf(hv[j].x, cv[i].x, acc[j][i]);
                    acc[j][i] = fmaf(hv[j].y, cv[i].y, acc[j][i]);
                    acc[j][i] = fmaf(hv[j].z, cv[i].z, acc[j][i]);
                    acc[j][i] = fmaf(hv[j].w, cv[i].w, acc[j][i]);
                }
        }

        // score = cnorm - 2*dot ; update running argmin (ascending c per lane keeps first-min)
        #pragma unroll
        for (int i = 0; i < 4; ++i) {
            const int c = ct * CT + cg + 16 * i;
            const float cn = cnorm[c];
            #pragma unroll
            for (int j = 0; j < 4; ++j) {
                const float s = fmaf(-2.f, acc[j][i], cn);
                if (s < minv[j]) { minv[j] = s; mini[j] = c; }
            }
        }
        __syncthreads();
    }

    // ---------------- Reduce across the 16 lanes sharing each row; gather ----------------
    #pragma unroll
    for (int j = 0; j < 4; ++j) {
        float v = minv[j];
        int  ix = mini[j];
        #pragma unroll
        for (int off = 1; off < 16; off <<= 1) {
            const float ov = __shfl_xor(v, off);
            const int   oi = __shfl_xor(ix, off);
            if (ov < v || (ov == v && oi < ix)) { v = ov; ix = oi; }
        }
        const int r = rg + 16 * j;
        const float4* src = (const float4*)(cb + (size_t)ix * KDIM);
        float4* dst = (float4*)(codes_out + (n0 + r) * KDIM);
        #pragma unroll
        for (int q = 0; q < 4; ++q) dst[cg + 16 * q] = src[cg + 16 * q];
        if (cg == 0) idx_out[n0 + r] = (float)ix;
    }
}

extern "C" void kernel_launch(void* const* d_in, const int* in_sizes, int n_in,
                              void* d_out, int out_size, void* d_ws, size_t ws_size,
                              hipStream_t stream) {
    const float* x    = (const float*)d_in[0];
    const float* W    = (const float*)d_in[1];
    const float* bvec = (const float*)d_in[2];
    const float* cb   = (const float*)d_in[3];

    float* codes_out = (float*)d_out;
    float* idx_out   = (float*)d_out + (size_t)NROWS * KDIM;
    float* cnorm     = (float*)d_ws;  // 16 KB scratch

    cnorm_kernel<<<NCODES / 4, 256, 0, stream>>>(cb, cnorm);
    vq_kernel<<<NROWS / ROWS, 256, 0, stream>>>(x, W, bvec, cb, cnorm, codes_out, idx_out);
}

// Round 4
// 734.617 us; speedup vs baseline: 1.2556x; 1.2556x over previous
//
#include <hip/hip_runtime.h>

#define NROWS   16384
#define INDIM   1024
#define KDIM    256
#define NCODES  4096
#define G_ROWS  32       // rows per gemm block
#define V_ROWS  64       // rows per vq block
#define NSTEP   128      // steps of 32 codes
#define BUFB    32896    // per staging buffer: hi 16384 + lo 16384 + cn 128

typedef float f32x4 __attribute__((ext_vector_type(4)));
typedef short short8 __attribute__((ext_vector_type(8)));
typedef unsigned short u16x8 __attribute__((ext_vector_type(8)));
typedef unsigned short u16x4 __attribute__((ext_vector_type(4)));

__device__ inline unsigned short f2bf(float f) {
    unsigned u = __builtin_bit_cast(unsigned, f);
    u = (u + 0x7fffu + ((u >> 16) & 1u)) >> 16;
    return (unsigned short)u;
}
__device__ inline float bf2f(unsigned short h) {
    unsigned u = ((unsigned)h) << 16;
    return __builtin_bit_cast(float, u);
}
__device__ inline f32x4 mfma16(short8 a, short8 b, f32x4 c) {
    return __builtin_amdgcn_mfma_f32_16x16x32_bf16(a, b, c, 0, 0, 0);
}

// ---------------- Kernel 1: h = x@W + b  (f32, h -> codes region of d_out) ----------------
__global__ __launch_bounds__(256) void gemm_kernel(const float* __restrict__ x,
                                                   const float* __restrict__ W,
                                                   const float* __restrict__ bvec,
                                                   float* __restrict__ hbuf) {
    const int t  = threadIdx.x;
    const int cg = t & 15;
    const int rg = t >> 4;           // 0..15 -> rows rg, rg+16
    const size_t n0 = (size_t)blockIdx.x * G_ROWS;
    const int c0 = cg * 16;

    float acc[2][16];
    #pragma unroll
    for (int j = 0; j < 2; ++j)
        #pragma unroll
        for (int cc = 0; cc < 16; ++cc) acc[j][cc] = 0.f;

    for (int k4 = 0; k4 < INDIM / 4; ++k4) {
        const int k = k4 * 4;
        f32x4 xv[2];
        #pragma unroll
        for (int j = 0; j < 2; ++j)
            xv[j] = *(const f32x4*)(x + (n0 + rg + 16 * j) * INDIM + k);
        f32x4 wv[4][4];
        #pragma unroll
        for (int kk = 0; kk < 4; ++kk)
            #pragma unroll
            for (int q = 0; q < 4; ++q)
                wv[kk][q] = *(const f32x4*)(W + (size_t)(k + kk) * KDIM + c0 + 4 * q);
        #pragma unroll
        for (int j = 0; j < 2; ++j)
            #pragma unroll
            for (int kk = 0; kk < 4; ++kk) {
                const float xs = xv[j][kk];
                #pragma unroll
                for (int q = 0; q < 4; ++q)
                    #pragma unroll
                    for (int e = 0; e < 4; ++e)
                        acc[j][4*q+e] = fmaf(xs, wv[kk][q][e], acc[j][4*q+e]);
            }
    }
    #pragma unroll
    for (int j = 0; j < 2; ++j) {
        float* dst = hbuf + (n0 + rg + 16 * j) * KDIM + c0;
        #pragma unroll
        for (int q = 0; q < 4; ++q) {
            f32x4 v;
            #pragma unroll
            for (int e = 0; e < 4; ++e) v[e] = acc[j][4*q+e] + bvec[c0 + 4*q + e];
            *(f32x4*)(dst + 4*q) = v;
        }
    }
}

// ---------------- Kernel 2: cnorm + optional bf16 hi/lo split of cb ----------------
__global__ __launch_bounds__(256) void prep_kernel(const float* __restrict__ cb,
                                                   float* __restrict__ cnorm,
                                                   unsigned short* __restrict__ cb_hi,
                                                   unsigned short* __restrict__ cb_lo,
                                                   int do_split) {
    const int c    = blockIdx.x * 4 + (threadIdx.x >> 6);
    const int lane = threadIdx.x & 63;
    f32x4 v = ((const f32x4*)(cb + (size_t)c * KDIM))[lane];
    if (do_split) {
        u16x4 h4, l4;
        #pragma unroll
        for (int j = 0; j < 4; ++j) {
            unsigned short h = f2bf(v[j]);
            h4[j] = h;
            l4[j] = f2bf(v[j] - bf2f(h));
        }
        *(u16x4*)(cb_hi + (size_t)c * KDIM + lane * 4) = h4;
        *(u16x4*)(cb_lo + (size_t)c * KDIM + lane * 4) = l4;
    }
    float s = v[0]*v[0] + v[1]*v[1] + v[2]*v[2] + v[3]*v[3];
    #pragma unroll
    for (int off = 1; off < 64; off <<= 1) s += __shfl_xor(s, off);
    if (lane == 0) cnorm[c] = s;
}

// stage helpers ----------------------------------------------------------------
template<int PRE>
__device__ inline void stage_load(const float* __restrict__ cb,
                                  const unsigned short* __restrict__ cb_hi,
                                  const unsigned short* __restrict__ cb_lo,
                                  int S, int sc, int sq, u16x8 rh[4], u16x8 rl[4]) {
    if (PRE) {
        const unsigned short* ph = cb_hi + ((size_t)(S * 32 + sc)) * KDIM + sq * 32;
        const unsigned short* pl = cb_lo + ((size_t)(S * 32 + sc)) * KDIM + sq * 32;
        #pragma unroll
        for (int q = 0; q < 4; ++q) {
            rh[q] = *(const u16x8*)(ph + q * 8);
            rl[q] = *(const u16x8*)(pl + q * 8);
        }
    } else {
        const float* p = cb + ((size_t)(S * 32 + sc)) * KDIM + sq * 32;
        #pragma unroll
        for (int q = 0; q < 4; ++q) {
            f32x4 a = *(const f32x4*)(p + q * 8);
            f32x4 b = *(const f32x4*)(p + q * 8 + 4);
            u16x8 uh, ul;
            #pragma unroll
            for (int jj = 0; jj < 4; ++jj) {
                unsigned short h0 = f2bf(a[jj]); uh[jj]   = h0; ul[jj]   = f2bf(a[jj] - bf2f(h0));
                unsigned short h1 = f2bf(b[jj]); uh[4+jj] = h1; ul[4+jj] = f2bf(b[jj] - bf2f(h1));
            }
            rh[q] = uh; rl[q] = ul;
        }
    }
}

__device__ inline void stage_write(char* __restrict__ buf, int t, int sc, int sq,
                                   const u16x8 rh[4], const u16x8 rl[4], f32x4 pcn) {
    #pragma unroll
    for (int q = 0; q < 4; ++q) {
        const unsigned off = (unsigned)((sc * 512 + (sq * 4 + q) * 16) ^ ((sc & 7) << 4));
        *(u16x8*)(buf + off)         = rh[q];
        *(u16x8*)(buf + 16384 + off) = rl[q];
    }
    if (t < 8) *(f32x4*)(buf + 32768 + t * 16) = pcn;
}

// ---------------- Kernel 3: MFMA distances + top-2 + exact refine + gather ----------------
template<int PRE>
__global__ __launch_bounds__(256) void vq_kernel(
    float* __restrict__ hbuf,                 // holds h; overwritten with codes
    const float* __restrict__ cb,
    const float* __restrict__ cnorm,
    const unsigned short* __restrict__ cb_hi,
    const unsigned short* __restrict__ cb_lo,
    float* __restrict__ idx_out)
{
    __shared__ __align__(16) char lds[2 * BUFB];

    const int t  = threadIdx.x;
    const int w  = t >> 6;
    const int l  = t & 63;
    const int nl = l & 15;
    const int g  = l >> 4;
    const size_t n0 = (size_t)blockIdx.x * V_ROWS;
    const int row = w * 16 + nl;              // this lane's output row (within block)
    float* hrow = hbuf + (n0 + row) * KDIM;

    // B-fragments: h hi + residual bf16 (exact h re-read from global at refine)
    u16x8 bhi[8], bmid[8];
    #pragma unroll
    for (int s = 0; s < 8; ++s) {
        f32x4 a = *(const f32x4*)(hrow + s * 32 + g * 8);
        f32x4 b = *(const f32x4*)(hrow + s * 32 + g * 8 + 4);
        u16x8 uh, um;
        #pragma unroll
        for (int jj = 0; jj < 4; ++jj) {
            unsigned short h0 = f2bf(a[jj]); uh[jj]   = h0; um[jj]   = f2bf(a[jj] - bf2f(h0));
            unsigned short h1 = f2bf(b[jj]); uh[4+jj] = h1; um[4+jj] = f2bf(b[jj] - bf2f(h1));
        }
        bhi[s] = uh; bmid[s] = um;
    }

    float v1 = 3.4e38f, v2 = 3.4e38f;
    int   i1 = 0, i2 = 0;

    const int sc = t >> 3;    // staging code 0..31
    const int sq = t & 7;     // staging chunk (32 elems)
    u16x8 rh[4], rl[4];
    f32x4 pcn = {0.f, 0.f, 0.f, 0.f};

    // prologue: stage step 0 into buffer 0
    stage_load<PRE>(cb, cb_hi, cb_lo, 0, sc, sq, rh, rl);
    if (t < 8) pcn = *(const f32x4*)(cnorm + t * 4);
    stage_write(lds, t, sc, sq, rh, rl, pcn);
    __syncthreads();

    for (int S = 0; S < NSTEP; ++S) {
        const int b = S & 1;
        if (S + 1 < NSTEP) {
            stage_load<PRE>(cb, cb_hi, cb_lo, S + 1, sc, sq, rh, rl);
            if (t < 8) pcn = *(const f32x4*)(cnorm + (S + 1) * 32 + t * 4);
        }
        {
            const char* hi = lds + b * BUFB;
            const char* lo = hi + 16384;
            const float* cn = (const float*)(hi + 32768);
            #pragma unroll
            for (int t2 = 0; t2 < 2; ++t2) {
                f32x4 acc = {0.f, 0.f, 0.f, 0.f};
                #pragma unroll
                for (int s = 0; s < 8; ++s) {
                    const unsigned roff =
                        (unsigned)(((t2 * 16 + nl) * 512 + (s * 4 + g) * 16) ^ ((nl & 7) << 4));
                    short8 ahi = *(const short8*)(hi + roff);
                    short8 alo = *(const short8*)(lo + roff);
                    acc = mfma16(ahi, __builtin_bit_cast(short8, bhi[s]),  acc);
                    acc = mfma16(ahi, __builtin_bit_cast(short8, bmid[s]), acc);
                    acc = mfma16(alo, __builtin_bit_cast(short8, bhi[s]),  acc);
                }
                #pragma unroll
                for (int r = 0; r < 4; ++r) {
                    const int cl = t2 * 16 + g * 4 + r;
                    const float d2 = cn[cl] - 2.0f * acc[r];
                    const int c = S * 32 + cl;
                    if (d2 < v1)      { v2 = v1; i2 = i1; v1 = d2; i1 = c; }
                    else if (d2 < v2) { v2 = d2; i2 = c; }
                }
            }
        }
        __syncthreads();                       // all waves done reading buffer b
        if (S + 1 < NSTEP) stage_write(lds + (b ^ 1) * BUFB, t, sc, sq, rh, rl, pcn);
        __syncthreads();                       // buffer b^1 ready for next step
    }

    // merge top-2 across the 4 k-lane-groups (same nl, different g)
    #pragma unroll
    for (int off = 16; off <= 32; off <<= 1) {
        float ov1 = __shfl_xor(v1, off); int oi1 = __shfl_xor(i1, off);
        float ov2 = __shfl_xor(v2, off); int oi2 = __shfl_xor(i2, off);
        if (ov1 < v1 || (ov1 == v1 && oi1 < i1)) {
            float tv = v1; int ti = i1; v1 = ov1; i1 = oi1; ov1 = tv; oi1 = ti;
            tv = v2; ti = i2; v2 = ov2; i2 = oi2; ov2 = tv; oi2 = ti;
        }
        if (ov1 < v2 || (ov1 == v2 && oi1 < i2)) { v2 = ov1; i2 = oi1; }
    }

    // defensive clamp: logic bug becomes wrong answer, not a fault
    i1 = (i1 < 0) ? 0 : (i1 > NCODES - 1 ? NCODES - 1 : i1);
    i2 = (i2 < 0) ? 0 : (i2 > NCODES - 1 ? NCODES - 1 : i2);

    // exact f32 refine of both candidates (h re-read from global, still intact)
    const float* cp1 = cb + (size_t)i1 * KDIM;
    const float* cp2 = cb + (size_t)i2 * KDIM;
    float da = 0.f, db = 0.f;
    #pragma unroll
    for (int s = 0; s < 8; ++s) {
        f32x4 h0 = *(const f32x4*)(hrow + s * 32 + g * 8);
        f32x4 h1 = *(const f32x4*)(hrow + s * 32 + g * 8 + 4);
        f32x4 a1 = *(const f32x4*)(cp1 + s * 32 + g * 8);
        f32x4 b1 = *(const f32x4*)(cp1 + s * 32 + g * 8 + 4);
        f32x4 a2 = *(const f32x4*)(cp2 + s * 32 + g * 8);
        f32x4 b2 = *(const f32x4*)(cp2 + s * 32 + g * 8 + 4);
        #pragma unroll
        for (int jj = 0; jj < 4; ++jj) {
            da = fmaf(a1[jj], h0[jj], da); da = fmaf(b1[jj], h1[jj], da);
            db = fmaf(a2[jj], h0[jj], db); db = fmaf(b2[jj], h1[jj], db);
        }
    }
    da += __shfl_xor(da, 16); da += __shfl_xor(da, 32);
    db += __shfl_xor(db, 16); db += __shfl_xor(db, 32);
    const float d2a = cnorm[i1] - 2.f * da;
    const float d2b = cnorm[i2] - 2.f * db;
    const int win = (d2a < d2b || (d2a == d2b && i1 < i2)) ? i1 : i2;

    // gather codes (overwrite h row) + write idx
    const float* cw = cb + (size_t)win * KDIM;
    #pragma unroll
    for (int s = 0; s < 8; ++s) {
        *(f32x4*)(hrow + s * 32 + g * 8)     = *(const f32x4*)(cw + s * 32 + g * 8);
        *(f32x4*)(hrow + s * 32 + g * 8 + 4) = *(const f32x4*)(cw + s * 32 + g * 8 + 4);
    }
    if (g == 0) idx_out[n0 + row] = (float)win;
}

extern "C" void kernel_launch(void* const* d_in, const int* in_sizes, int n_in,
                              void* d_out, int out_size, void* d_ws, size_t ws_size,
                              hipStream_t stream) {
    (void)in_sizes; (void)n_in; (void)out_size;
    const float* x    = (const float*)d_in[0];
    const float* W    = (const float*)d_in[1];
    const float* bvec = (const float*)d_in[2];
    const float* cb   = (const float*)d_in[3];

    float* codes_out = (float*)d_out;                       // doubles as h buffer
    float* idx_out   = (float*)d_out + (size_t)NROWS * KDIM;

    float* cnorm = (float*)d_ws;
    unsigned short* cb_hi = (unsigned short*)((char*)d_ws + 16384);
    unsigned short* cb_lo = cb_hi + (size_t)NCODES * KDIM;
    const size_t need = 16384 + (size_t)NCODES * KDIM * 2 * sizeof(unsigned short);
    const int pre = (ws_size >= need) ? 1 : 0;

    gemm_kernel<<<NROWS / G_ROWS, 256, 0, stream>>>(x, W, bvec, codes_out);
    prep_kernel<<<NCODES / 4, 256, 0, stream>>>(cb, cnorm, cb_hi, cb_lo, pre);
    if (pre)
        vq_kernel<1><<<NROWS / V_ROWS, 256, 0, stream>>>(codes_out, cb, cnorm, cb_hi, cb_lo, idx_out);
    else
        vq_kernel<0><<<NROWS / V_ROWS, 256, 0, stream>>>(codes_out, cb, cnorm, cb_hi, cb_lo, idx_out);
}

// Round 6
// 352.247 us; speedup vs baseline: 2.6186x; 2.0855x over previous
//
#include <hip/hip_runtime.h>

#define NROWS   16384
#define INDIM   1024
#define KDIM    256
#define NCODES  4096
#define G_ROWS  32       // rows per fallback-gemm block
#define V_ROWS  64       // rows per vq block
#define NSTEP   128      // vq: steps of 32 codes
#define BUFB    32896    // vq staging buffer: hi 16384 + lo 16384 + cn 128

// mfma-gemm geometry
#define MG_ROWS 64       // rows per block
#define MG_KC   64       // k per chunk
#define MG_NCH  (INDIM / MG_KC)   // 16 chunks
// LDS offsets (bytes): x hi/md/lo 3x8KB, W hi/md/lo 3x32KB
#define XA_HI   0
#define XA_MD   8192
#define XA_LO   16384
#define WA_HI   24576
#define WA_MD   57344
#define WA_LO   90112
#define MG_LDS  122880

typedef float f32x4 __attribute__((ext_vector_type(4)));
typedef short short8 __attribute__((ext_vector_type(8)));
typedef unsigned short u16x8 __attribute__((ext_vector_type(8)));
typedef unsigned short u16x4 __attribute__((ext_vector_type(4)));

__device__ inline unsigned short f2bf(float f) {
    unsigned u = __builtin_bit_cast(unsigned, f);
    u = (u + 0x7fffu + ((u >> 16) & 1u)) >> 16;
    return (unsigned short)u;
}
__device__ inline float bf2f(unsigned short h) {
    unsigned u = ((unsigned)h) << 16;
    return __builtin_bit_cast(float, u);
}
__device__ inline f32x4 mfma16(u16x8 a, u16x8 b, f32x4 c) {
    return __builtin_amdgcn_mfma_f32_16x16x32_bf16(
        __builtin_bit_cast(short8, a), __builtin_bit_cast(short8, b), c, 0, 0, 0);
}

// ---------------- prep: W[1024][256] f32 -> W_T 3-way bf16 split [256][1024] ----------------
__global__ __launch_bounds__(256) void wprep_kernel(const float* __restrict__ W,
                                                    unsigned short* __restrict__ wt_hi,
                                                    unsigned short* __restrict__ wt_md,
                                                    unsigned short* __restrict__ wt_lo) {
    const int t = threadIdx.x;
    const int k = blockIdx.x * 4 + (t >> 6);
    const int c0 = (t & 63) * 4;
    f32x4 v = *(const f32x4*)(W + (size_t)k * KDIM + c0);
    #pragma unroll
    for (int i = 0; i < 4; ++i) {
        const unsigned short h = f2bf(v[i]);
        const float r1 = v[i] - bf2f(h);
        const unsigned short m = f2bf(r1);
        const unsigned short lo = f2bf(r1 - bf2f(m));
        wt_hi[(size_t)(c0 + i) * INDIM + k] = h;
        wt_md[(size_t)(c0 + i) * INDIM + k] = m;
        wt_lo[(size_t)(c0 + i) * INDIM + k] = lo;
    }
}

// ---------------- MFMA gemm: h = x@W + b (6-pass 3-way split, f32-class accuracy) ----------------
__global__ __launch_bounds__(256, 1) void gemm_mfma_kernel(const float* __restrict__ x,
                                                           const unsigned short* __restrict__ wt_hi,
                                                           const unsigned short* __restrict__ wt_md,
                                                           const unsigned short* __restrict__ wt_lo,
                                                           const float* __restrict__ bvec,
                                                           float* __restrict__ hbuf) {
    __shared__ __align__(16) char lds[MG_LDS];

    const int t  = threadIdx.x;
    const int w  = t >> 6;
    const int l  = t & 63;
    const int nl = l & 15;
    const int g  = l >> 4;
    const size_t n0 = (size_t)blockIdx.x * MG_ROWS;

    const int sr = t >> 2;         // x stage: row 0..63
    const int sq = t & 3;          // x stage: 16-elem k-group
    const int scol = t;            // W stage: col 0..255

    f32x4 acc[4][4];               // [ct][rs]
    #pragma unroll
    for (int a = 0; a < 4; ++a)
        #pragma unroll
        for (int b = 0; b < 4; ++b) acc[a][b] = (f32x4){0.f, 0.f, 0.f, 0.f};

    for (int kc = 0; kc < MG_NCH; ++kc) {
        // ---- global loads to regs (overlaps previous chunk's MFMAs) ----
        f32x4 xr[4];
        #pragma unroll
        for (int q = 0; q < 4; ++q)
            xr[q] = *(const f32x4*)(x + (n0 + sr) * INDIM + kc * MG_KC + sq * 16 + 4 * q);
        u16x8 wh[8], wm[8], wl[8];
        {
            const size_t wb = (size_t)scol * INDIM + kc * MG_KC;
            #pragma unroll
            for (int q = 0; q < 8; ++q) {
                wh[q] = *(const u16x8*)(wt_hi + wb + q * 8);
                wm[q] = *(const u16x8*)(wt_md + wb + q * 8);
                wl[q] = *(const u16x8*)(wt_lo + wb + q * 8);
            }
        }
        __syncthreads();   // previous compute done; safe to overwrite LDS

        // ---- x: 3-way split + swizzled LDS write ----
        #pragma unroll
        for (int j = 0; j < 2; ++j) {
            u16x8 xh, xm, xl;
            #pragma unroll
            for (int e = 0; e < 4; ++e) {
                const float a0 = xr[2*j][e], a1 = xr[2*j+1][e];
                const unsigned short h0 = f2bf(a0);
                const float r10 = a0 - bf2f(h0);
                const unsigned short m0 = f2bf(r10);
                const unsigned short l0 = f2bf(r10 - bf2f(m0));
                const unsigned short h1 = f2bf(a1);
                const float r11 = a1 - bf2f(h1);
                const unsigned short m1 = f2bf(r11);
                const unsigned short l1 = f2bf(r11 - bf2f(m1));
                xh[e] = h0; xh[4+e] = h1;
                xm[e] = m0; xm[4+e] = m1;
                xl[e] = l0; xl[4+e] = l1;
            }
            const unsigned off = (unsigned)(sr * 128 + (((sq * 2 + j) * 16) ^ ((sr & 7) << 4)));
            *(u16x8*)(lds + XA_HI + off) = xh;
            *(u16x8*)(lds + XA_MD + off) = xm;
            *(u16x8*)(lds + XA_LO + off) = xl;
        }
        // ---- W: swizzled LDS write ----
        #pragma unroll
        for (int q = 0; q < 8; ++q) {
            const unsigned off = (unsigned)(scol * 128 + ((q * 16) ^ ((scol & 7) << 4)));
            *(u16x8*)(lds + WA_HI + off) = wh[q];
            *(u16x8*)(lds + WA_MD + off) = wm[q];
            *(u16x8*)(lds + WA_LO + off) = wl[q];
        }
        __syncthreads();   // tile ready

        // ---- compute: 2 k-subtiles x 4 col-tiles x 4 row-sets x 6 passes ----
        #pragma unroll
        for (int s = 0; s < 2; ++s) {
            u16x8 bh[4], bm[4], bl[4], ah[4], am[4], al[4];
            #pragma unroll
            for (int rs = 0; rs < 4; ++rs) {
                const int row = rs * 16 + nl;
                const unsigned off = (unsigned)(row * 128 + (((s * 4 + g) * 16) ^ ((row & 7) << 4)));
                bh[rs] = *(const u16x8*)(lds + XA_HI + off);
                bm[rs] = *(const u16x8*)(lds + XA_MD + off);
                bl[rs] = *(const u16x8*)(lds + XA_LO + off);
            }
            #pragma unroll
            for (int ct = 0; ct < 4; ++ct) {
                const int col = w * 64 + ct * 16 + nl;
                const unsigned off = (unsigned)(col * 128 + (((s * 4 + g) * 16) ^ ((col & 7) << 4)));
                ah[ct] = *(const u16x8*)(lds + WA_HI + off);
                am[ct] = *(const u16x8*)(lds + WA_MD + off);
                al[ct] = *(const u16x8*)(lds + WA_LO + off);
            }
            #pragma unroll
            for (int ct = 0; ct < 4; ++ct)
                #pragma unroll
                for (int rs = 0; rs < 4; ++rs) {
                    acc[ct][rs] = mfma16(ah[ct], bh[rs], acc[ct][rs]);  // hi*hi
                    acc[ct][rs] = mfma16(ah[ct], bm[rs], acc[ct][rs]);  // hi*mid
                    acc[ct][rs] = mfma16(am[ct], bh[rs], acc[ct][rs]);  // mid*hi
                    acc[ct][rs] = mfma16(ah[ct], bl[rs], acc[ct][rs]);  // hi*lo
                    acc[ct][rs] = mfma16(al[ct], bh[rs], acc[ct][rs]);  // lo*hi
                    acc[ct][rs] = mfma16(am[ct], bm[rs], acc[ct][rs]);  // mid*mid
                }
        }
    }

    // ---- epilogue: + bias, store h ----
    #pragma unroll
    for (int ct = 0; ct < 4; ++ct) {
        float bv[4];
        #pragma unroll
        for (int r = 0; r < 4; ++r) bv[r] = bvec[w * 64 + ct * 16 + g * 4 + r];
        #pragma unroll
        for (int rs = 0; rs < 4; ++rs) {
            const size_t row = n0 + rs * 16 + nl;
            #pragma unroll
            for (int r = 0; r < 4; ++r)
                hbuf[row * KDIM + w * 64 + ct * 16 + g * 4 + r] = acc[ct][rs][r] + bv[r];
        }
    }
}

// ---------------- fallback f32 gemm (r4-proven; launch_bounds fixed vs r4's spill) ----------------
__global__ __launch_bounds__(256, 2) void gemm_fb_kernel(const float* __restrict__ x,
                                                         const float* __restrict__ W,
                                                         const float* __restrict__ bvec,
                                                         float* __restrict__ hbuf) {
    const int t  = threadIdx.x;
    const int cg = t & 15;
    const int rg = t >> 4;
    const size_t n0 = (size_t)blockIdx.x * G_ROWS;
    const int c0 = cg * 16;

    float acc[2][16];
    #pragma unroll
    for (int j = 0; j < 2; ++j)
        #pragma unroll
        for (int cc = 0; cc < 16; ++cc) acc[j][cc] = 0.f;

    for (int k4 = 0; k4 < INDIM / 4; ++k4) {
        const int k = k4 * 4;
        f32x4 xv[2];
        #pragma unroll
        for (int j = 0; j < 2; ++j)
            xv[j] = *(const f32x4*)(x + (n0 + rg + 16 * j) * INDIM + k);
        f32x4 wv[4][4];
        #pragma unroll
        for (int kk = 0; kk < 4; ++kk)
            #pragma unroll
            for (int q = 0; q < 4; ++q)
                wv[kk][q] = *(const f32x4*)(W + (size_t)(k + kk) * KDIM + c0 + 4 * q);
        #pragma unroll
        for (int j = 0; j < 2; ++j)
            #pragma unroll
            for (int kk = 0; kk < 4; ++kk) {
                const float xs = xv[j][kk];
                #pragma unroll
                for (int q = 0; q < 4; ++q)
                    #pragma unroll
                    for (int e = 0; e < 4; ++e)
                        acc[j][4*q+e] = fmaf(xs, wv[kk][q][e], acc[j][4*q+e]);
            }
    }
    #pragma unroll
    for (int j = 0; j < 2; ++j) {
        float* dst = hbuf + (n0 + rg + 16 * j) * KDIM + c0;
        #pragma unroll
        for (int q = 0; q < 4; ++q) {
            f32x4 v;
            #pragma unroll
            for (int e = 0; e < 4; ++e) v[e] = acc[j][4*q+e] + bvec[c0 + 4*q + e];
            *(f32x4*)(dst + 4*q) = v;
        }
    }
}

// ---------------- prep: cnorm + optional bf16 hi/lo split of cb ----------------
__global__ __launch_bounds__(256) void prep_kernel(const float* __restrict__ cb,
                                                   float* __restrict__ cnorm,
                                                   unsigned short* __restrict__ cb_hi,
                                                   unsigned short* __restrict__ cb_lo,
                                                   int do_split) {
    const int c    = blockIdx.x * 4 + (threadIdx.x >> 6);
    const int lane = threadIdx.x & 63;
    f32x4 v = ((const f32x4*)(cb + (size_t)c * KDIM))[lane];
    if (do_split) {
        u16x4 h4, l4;
        #pragma unroll
        for (int j = 0; j < 4; ++j) {
            unsigned short h = f2bf(v[j]);
            h4[j] = h;
            l4[j] = f2bf(v[j] - bf2f(h));
        }
        *(u16x4*)(cb_hi + (size_t)c * KDIM + lane * 4) = h4;
        *(u16x4*)(cb_lo + (size_t)c * KDIM + lane * 4) = l4;
    }
    float s = v[0]*v[0] + v[1]*v[1] + v[2]*v[2] + v[3]*v[3];
    #pragma unroll
    for (int off = 1; off < 64; off <<= 1) s += __shfl_xor(s, off);
    if (lane == 0) cnorm[c] = s;
}

// vq stage helpers ----------------------------------------------------------------
template<int PRE>
__device__ inline void stage_load(const float* __restrict__ cb,
                                  const unsigned short* __restrict__ cb_hi,
                                  const unsigned short* __restrict__ cb_lo,
                                  int S, int sc, int sq, u16x8 rh[4], u16x8 rl[4]) {
    if (PRE) {
        const unsigned short* ph = cb_hi + ((size_t)(S * 32 + sc)) * KDIM + sq * 32;
        const unsigned short* pl = cb_lo + ((size_t)(S * 32 + sc)) * KDIM + sq * 32;
        #pragma unroll
        for (int q = 0; q < 4; ++q) {
            rh[q] = *(const u16x8*)(ph + q * 8);
            rl[q] = *(const u16x8*)(pl + q * 8);
        }
    } else {
        const float* p = cb + ((size_t)(S * 32 + sc)) * KDIM + sq * 32;
        #pragma unroll
        for (int q = 0; q < 4; ++q) {
            f32x4 a = *(const f32x4*)(p + q * 8);
            f32x4 b = *(const f32x4*)(p + q * 8 + 4);
            u16x8 uh, ul;
            #pragma unroll
            for (int jj = 0; jj < 4; ++jj) {
                unsigned short h0 = f2bf(a[jj]); uh[jj]   = h0; ul[jj]   = f2bf(a[jj] - bf2f(h0));
                unsigned short h1 = f2bf(b[jj]); uh[4+jj] = h1; ul[4+jj] = f2bf(b[jj] - bf2f(h1));
            }
            rh[q] = uh; rl[q] = ul;
        }
    }
}

__device__ inline void stage_write(char* __restrict__ buf, int t, int sc, int sq,
                                   const u16x8 rh[4], const u16x8 rl[4], f32x4 pcn) {
    #pragma unroll
    for (int q = 0; q < 4; ++q) {
        const unsigned off = (unsigned)((sc * 512 + (sq * 4 + q) * 16) ^ ((sc & 7) << 4));
        *(u16x8*)(buf + off)         = rh[q];
        *(u16x8*)(buf + 16384 + off) = rl[q];
    }
    if (t < 8) *(f32x4*)(buf + 32768 + t * 16) = pcn;
}

// ---------------- vq: MFMA distances + top-2 + exact refine + gather (r4-proven) ----------------
template<int PRE>
__global__ __launch_bounds__(256) void vq_kernel(
    float* __restrict__ hbuf,
    const float* __restrict__ cb,
    const float* __restrict__ cnorm,
    const unsigned short* __restrict__ cb_hi,
    const unsigned short* __restrict__ cb_lo,
    float* __restrict__ idx_out)
{
    __shared__ __align__(16) char lds[2 * BUFB];

    const int t  = threadIdx.x;
    const int w  = t >> 6;
    const int l  = t & 63;
    const int nl = l & 15;
    const int g  = l >> 4;
    const size_t n0 = (size_t)blockIdx.x * V_ROWS;
    const int row = w * 16 + nl;
    float* hrow = hbuf + (n0 + row) * KDIM;

    u16x8 bhi[8], bmid[8];
    #pragma unroll
    for (int s = 0; s < 8; ++s) {
        f32x4 a = *(const f32x4*)(hrow + s * 32 + g * 8);
        f32x4 b = *(const f32x4*)(hrow + s * 32 + g * 8 + 4);
        u16x8 uh, um;
        #pragma unroll
        for (int jj = 0; jj < 4; ++jj) {
            unsigned short h0 = f2bf(a[jj]); uh[jj]   = h0; um[jj]   = f2bf(a[jj] - bf2f(h0));
            unsigned short h1 = f2bf(b[jj]); uh[4+jj] = h1; um[4+jj] = f2bf(b[jj] - bf2f(h1));
        }
        bhi[s] = uh; bmid[s] = um;
    }

    float v1 = 3.4e38f, v2 = 3.4e38f;
    int   i1 = 0, i2 = 0;

    const int sc = t >> 3;
    const int sq = t & 7;
    u16x8 rh[4], rl[4];
    f32x4 pcn = {0.f, 0.f, 0.f, 0.f};

    stage_load<PRE>(cb, cb_hi, cb_lo, 0, sc, sq, rh, rl);
    if (t < 8) pcn = *(const f32x4*)(cnorm + t * 4);
    stage_write(lds, t, sc, sq, rh, rl, pcn);
    __syncthreads();

    for (int S = 0; S < NSTEP; ++S) {
        const int b = S & 1;
        if (S + 1 < NSTEP) {
            stage_load<PRE>(cb, cb_hi, cb_lo, S + 1, sc, sq, rh, rl);
            if (t < 8) pcn = *(const f32x4*)(cnorm + (S + 1) * 32 + t * 4);
        }
        {
            const char* hi = lds + b * BUFB;
            const char* lo = hi + 16384;
            const float* cn = (const float*)(hi + 32768);
            #pragma unroll
            for (int t2 = 0; t2 < 2; ++t2) {
                f32x4 acc = {0.f, 0.f, 0.f, 0.f};
                #pragma unroll
                for (int s = 0; s < 8; ++s) {
                    const unsigned roff =
                        (unsigned)(((t2 * 16 + nl) * 512 + (s * 4 + g) * 16) ^ ((nl & 7) << 4));
                    u16x8 ahi = *(const u16x8*)(hi + roff);
                    u16x8 alo = *(const u16x8*)(lo + roff);
                    acc = mfma16(ahi, bhi[s],  acc);
                    acc = mfma16(ahi, bmid[s], acc);
                    acc = mfma16(alo, bhi[s],  acc);
                }
                #pragma unroll
                for (int r = 0; r < 4; ++r) {
                    const int cl = t2 * 16 + g * 4 + r;
                    const float d2 = cn[cl] - 2.0f * acc[r];
                    const int c = S * 32 + cl;
                    if (d2 < v1)      { v2 = v1; i2 = i1; v1 = d2; i1 = c; }
                    else if (d2 < v2) { v2 = d2; i2 = c; }
                }
            }
        }
        __syncthreads();
        if (S + 1 < NSTEP) stage_write(lds + (b ^ 1) * BUFB, t, sc, sq, rh, rl, pcn);
        __syncthreads();
    }

    #pragma unroll
    for (int off = 16; off <= 32; off <<= 1) {
        float ov1 = __shfl_xor(v1, off); int oi1 = __shfl_xor(i1, off);
        float ov2 = __shfl_xor(v2, off); int oi2 = __shfl_xor(i2, off);
        if (ov1 < v1 || (ov1 == v1 && oi1 < i1)) {
            float tv = v1; int ti = i1; v1 = ov1; i1 = oi1; ov1 = tv; oi1 = ti;
            tv = v2; ti = i2; v2 = ov2; i2 = oi2; ov2 = tv; oi2 = ti;
        }
        if (ov1 < v2 || (ov1 == v2 && oi1 < i2)) { v2 = ov1; i2 = oi1; }
    }

    i1 = (i1 < 0) ? 0 : (i1 > NCODES - 1 ? NCODES - 1 : i1);
    i2 = (i2 < 0) ? 0 : (i2 > NCODES - 1 ? NCODES - 1 : i2);

    const float* cp1 = cb + (size_t)i1 * KDIM;
    const float* cp2 = cb + (size_t)i2 * KDIM;
    float da = 0.f, db = 0.f;
    #pragma unroll
    for (int s = 0; s < 8; ++s) {
        f32x4 h0 = *(const f32x4*)(hrow + s * 32 + g * 8);
        f32x4 h1 = *(const f32x4*)(hrow + s * 32 + g * 8 + 4);
        f32x4 a1 = *(const f32x4*)(cp1 + s * 32 + g * 8);
        f32x4 b1 = *(const f32x4*)(cp1 + s * 32 + g * 8 + 4);
        f32x4 a2 = *(const f32x4*)(cp2 + s * 32 + g * 8);
        f32x4 b2 = *(const f32x4*)(cp2 + s * 32 + g * 8 + 4);
        #pragma unroll
        for (int jj = 0; jj < 4; ++jj) {
            da = fmaf(a1[jj], h0[jj], da); da = fmaf(b1[jj], h1[jj], da);
            db = fmaf(a2[jj], h0[jj], db); db = fmaf(b2[jj], h1[jj], db);
        }
    }
    da += __shfl_xor(da, 16); da += __shfl_xor(da, 32);
    db += __shfl_xor(db, 16); db += __shfl_xor(db, 32);
    const float d2a = cnorm[i1] - 2.f * da;
    const float d2b = cnorm[i2] - 2.f * db;
    const int win = (d2a < d2b || (d2a == d2b && i1 < i2)) ? i1 : i2;

    const float* cw = cb + (size_t)win * KDIM;
    #pragma unroll
    for (int s = 0; s < 8; ++s) {
        *(f32x4*)(hrow + s * 32 + g * 8)     = *(const f32x4*)(cw + s * 32 + g * 8);
        *(f32x4*)(hrow + s * 32 + g * 8 + 4) = *(const f32x4*)(cw + s * 32 + g * 8 + 4);
    }
    if (g == 0) idx_out[n0 + row] = (float)win;
}

extern "C" void kernel_launch(void* const* d_in, const int* in_sizes, int n_in,
                              void* d_out, int out_size, void* d_ws, size_t ws_size,
                              hipStream_t stream) {
    (void)in_sizes; (void)n_in; (void)out_size;
    const float* x    = (const float*)d_in[0];
    const float* W    = (const float*)d_in[1];
    const float* bvec = (const float*)d_in[2];
    const float* cb   = (const float*)d_in[3];

    float* codes_out = (float*)d_out;                       // doubles as h buffer
    float* idx_out   = (float*)d_out + (size_t)NROWS * KDIM;

    // ws layout: cnorm[16KB] | cb_hi[2MB] | cb_lo[2MB] | wt_hi/md/lo[3x0.5MB]
    float* cnorm = (float*)d_ws;
    unsigned short* cb_hi = (unsigned short*)((char*)d_ws + 16384);
    unsigned short* cb_lo = cb_hi + (size_t)NCODES * KDIM;
    unsigned short* wt_hi = cb_lo + (size_t)NCODES * KDIM;
    unsigned short* wt_md = wt_hi + (size_t)INDIM * KDIM;
    unsigned short* wt_lo = wt_md + (size_t)INDIM * KDIM;

    const size_t need_cb   = 16384 + (size_t)NCODES * KDIM * 2 * sizeof(unsigned short);
    const size_t need_full = need_cb + (size_t)INDIM * KDIM * 3 * sizeof(unsigned short);

    const int pre_cb = (ws_size >= need_cb) ? 1 : 0;
    const int fast_g = (ws_size >= need_full) ? 1 : 0;

    if (fast_g) {
        wprep_kernel<<<INDIM / 4, 256, 0, stream>>>(W, wt_hi, wt_md, wt_lo);
        gemm_mfma_kernel<<<NROWS / MG_ROWS, 256, 0, stream>>>(x, wt_hi, wt_md, wt_lo, bvec, codes_out);
    } else {
        gemm_fb_kernel<<<NROWS / G_ROWS, 256, 0, stream>>>(x, W, bvec, codes_out);
    }
    prep_kernel<<<NCODES / 4, 256, 0, stream>>>(cb, cnorm, cb_hi, cb_lo, pre_cb);
    if (pre_cb)
        vq_kernel<1><<<NROWS / V_ROWS, 256, 0, stream>>>(codes_out, cb, cnorm, cb_hi, cb_lo, idx_out);
    else
        vq_kernel<0><<<NROWS / V_ROWS, 256, 0, stream>>>(codes_out, cb, cnorm, cb_hi, cb_lo, idx_out);
}

// Round 7
// 304.211 us; speedup vs baseline: 3.0321x; 1.1579x over previous
//
#include <hip/hip_runtime.h>

#define NROWS   16384
#define INDIM   1024
#define KDIM    256
#define NCODES  4096
#define G_ROWS  32       // rows per fallback-gemm block
#define V_ROWS  64       // rows per vq block
#define NSTEP   128      // vq: steps of 32 codes

// vq LDS: 2 buffers x (hi 16KB + lo 16KB); [t2][s][lane] lane-linear
#define VBUF    32768

// gemm LDS: X 3x8KB ([s][rs][lane]) + W 3x32KB ([s][cidx][lane])
#define MG_ROWS 64
#define MG_KC   64
#define MG_NCH  (INDIM / MG_KC)   // 16
#define XP(p)   ((p) * 8192)
#define WP(p)   (24576 + (p) * 32768)
#define MG_LDS  122880

typedef float f32x4 __attribute__((ext_vector_type(4)));
typedef short short8 __attribute__((ext_vector_type(8)));
typedef unsigned short u16x8 __attribute__((ext_vector_type(8)));
typedef unsigned short u16x4 __attribute__((ext_vector_type(4)));

__device__ inline unsigned short f2bf(float f) {
    unsigned u = __builtin_bit_cast(unsigned, f);
    u = (u + 0x7fffu + ((u >> 16) & 1u)) >> 16;
    return (unsigned short)u;
}
__device__ inline float bf2f(unsigned short h) {
    unsigned u = ((unsigned)h) << 16;
    return __builtin_bit_cast(float, u);
}
__device__ inline f32x4 mfma16(u16x8 a, u16x8 b, f32x4 c) {
    return __builtin_amdgcn_mfma_f32_16x16x32_bf16(
        __builtin_bit_cast(short8, a), __builtin_bit_cast(short8, b), c, 0, 0, 0);
}

// ---------------- prep: W[1024][256] f32 -> W_T 3-way bf16 split [256][1024] ----------------
__global__ __launch_bounds__(256) void wprep_kernel(const float* __restrict__ W,
                                                    unsigned short* __restrict__ wt_hi,
                                                    unsigned short* __restrict__ wt_md,
                                                    unsigned short* __restrict__ wt_lo) {
    const int t = threadIdx.x;
    const int k = blockIdx.x * 4 + (t >> 6);
    const int c0 = (t & 63) * 4;
    f32x4 v = *(const f32x4*)(W + (size_t)k * KDIM + c0);
    #pragma unroll
    for (int i = 0; i < 4; ++i) {
        const unsigned short h = f2bf(v[i]);
        const float r1 = v[i] - bf2f(h);
        const unsigned short m = f2bf(r1);
        const unsigned short lo = f2bf(r1 - bf2f(m));
        wt_hi[(size_t)(c0 + i) * INDIM + k] = h;
        wt_md[(size_t)(c0 + i) * INDIM + k] = m;
        wt_lo[(size_t)(c0 + i) * INDIM + k] = lo;
    }
}

// ---------------- MFMA gemm: h = x@W + b (6-pass 3-way split, f32-class accuracy) ----------------
__global__ __launch_bounds__(256, 1) void gemm_mfma_kernel(const float* __restrict__ x,
                                                           const unsigned short* __restrict__ wt_hi,
                                                           const unsigned short* __restrict__ wt_md,
                                                           const unsigned short* __restrict__ wt_lo,
                                                           const float* __restrict__ bvec,
                                                           float* __restrict__ hbuf) {
    __shared__ __align__(16) char lds[MG_LDS];

    const int t  = threadIdx.x;
    const int w  = t >> 6;
    const int l  = t & 63;
    const int nl = l & 15;
    const int g  = l >> 4;
    const size_t n0 = (size_t)blockIdx.x * MG_ROWS;
    const int lb = l * 16;          // lane byte offset within a 1KB chunk

    f32x4 acc[4][4];                // [ct][rs]
    #pragma unroll
    for (int a = 0; a < 4; ++a)
        #pragma unroll
        for (int b = 0; b < 4; ++b) acc[a][b] = (f32x4){0.f, 0.f, 0.f, 0.f};

    for (int kc = 0; kc < MG_NCH; ++kc) {
        // ---- global loads to regs (overlap previous chunk's MFMAs) ----
        // X: this thread covers combos idx = w*2 + c  -> (sX = idx>>2, rsX = idx&3)
        f32x4 xa[2], xb[2];
        #pragma unroll
        for (int c = 0; c < 2; ++c) {
            const int idx = w * 2 + c;
            const int sX = idx >> 2, rsX = idx & 3;
            const float* p = x + (n0 + rsX * 16 + nl) * INDIM + kc * MG_KC + sX * 32 + g * 8;
            xa[c] = *(const f32x4*)(p);
            xb[c] = *(const f32x4*)(p + 4);
        }
        // W: this wave stages exactly its own quarter: cidx = w*4+ci, s = 0..1
        u16x8 wh[8], wm[8], wl[8];
        #pragma unroll
        for (int ci = 0; ci < 4; ++ci)
            #pragma unroll
            for (int sW = 0; sW < 2; ++sW) {
                const int q = ci * 2 + sW;
                const size_t off = (size_t)((w * 4 + ci) * 16 + nl) * INDIM
                                 + kc * MG_KC + sW * 32 + g * 8;
                wh[q] = *(const u16x8*)(wt_hi + off);
                wm[q] = *(const u16x8*)(wt_md + off);
                wl[q] = *(const u16x8*)(wt_lo + off);
            }
        __syncthreads();   // previous compute done; safe to overwrite LDS

        // ---- X: 3-way split + lane-linear LDS write ----
        #pragma unroll
        for (int c = 0; c < 2; ++c) {
            const int idx = w * 2 + c;
            const int sX = idx >> 2, rsX = idx & 3;
            u16x8 xh, xm, xl;
            #pragma unroll
            for (int e = 0; e < 4; ++e) {
                const float a0 = xa[c][e], a1 = xb[c][e];
                const unsigned short h0 = f2bf(a0);
                const float r10 = a0 - bf2f(h0);
                const unsigned short m0 = f2bf(r10);
                const unsigned short l0 = f2bf(r10 - bf2f(m0));
                const unsigned short h1 = f2bf(a1);
                const float r11 = a1 - bf2f(h1);
                const unsigned short m1 = f2bf(r11);
                const unsigned short l1 = f2bf(r11 - bf2f(m1));
                xh[e] = h0; xh[4+e] = h1;
                xm[e] = m0; xm[4+e] = m1;
                xl[e] = l0; xl[4+e] = l1;
            }
            const int base = (sX * 4 + rsX) * 1024 + lb;
            *(u16x8*)(lds + XP(0) + base) = xh;
            *(u16x8*)(lds + XP(1) + base) = xm;
            *(u16x8*)(lds + XP(2) + base) = xl;
        }
        // ---- W: lane-linear LDS write ----
        #pragma unroll
        for (int ci = 0; ci < 4; ++ci)
            #pragma unroll
            for (int sW = 0; sW < 2; ++sW) {
                const int q = ci * 2 + sW;
                const int base = (sW * 16 + w * 4 + ci) * 1024 + lb;
                *(u16x8*)(lds + WP(0) + base) = wh[q];
                *(u16x8*)(lds + WP(1) + base) = wm[q];
                *(u16x8*)(lds + WP(2) + base) = wl[q];
            }
        __syncthreads();   // tile ready

        // ---- compute: 2 k-subtiles x 4 col-tiles x 4 row-sets x 6 passes ----
        #pragma unroll
        for (int s = 0; s < 2; ++s) {
            u16x8 bh[4], bm[4], bl[4], ah[4], am[4], al[4];
            #pragma unroll
            for (int rs = 0; rs < 4; ++rs) {
                const int base = (s * 4 + rs) * 1024 + lb;
                bh[rs] = *(const u16x8*)(lds + XP(0) + base);
                bm[rs] = *(const u16x8*)(lds + XP(1) + base);
                bl[rs] = *(const u16x8*)(lds + XP(2) + base);
            }
            #pragma unroll
            for (int ct = 0; ct < 4; ++ct) {
                const int base = (s * 16 + w * 4 + ct) * 1024 + lb;
                ah[ct] = *(const u16x8*)(lds + WP(0) + base);
                am[ct] = *(const u16x8*)(lds + WP(1) + base);
                al[ct] = *(const u16x8*)(lds + WP(2) + base);
            }
            #pragma unroll
            for (int ct = 0; ct < 4; ++ct)
                #pragma unroll
                for (int rs = 0; rs < 4; ++rs) {
                    acc[ct][rs] = mfma16(ah[ct], bh[rs], acc[ct][rs]);  // hi*hi
                    acc[ct][rs] = mfma16(ah[ct], bm[rs], acc[ct][rs]);  // hi*mid
                    acc[ct][rs] = mfma16(am[ct], bh[rs], acc[ct][rs]);  // mid*hi
                    acc[ct][rs] = mfma16(ah[ct], bl[rs], acc[ct][rs]);  // hi*lo
                    acc[ct][rs] = mfma16(al[ct], bh[rs], acc[ct][rs]);  // lo*hi
                    acc[ct][rs] = mfma16(am[ct], bm[rs], acc[ct][rs]);  // mid*mid
                }
        }
    }

    // ---- epilogue: + bias, store h ----
    #pragma unroll
    for (int ct = 0; ct < 4; ++ct) {
        float bv[4];
        #pragma unroll
        for (int r = 0; r < 4; ++r) bv[r] = bvec[w * 64 + ct * 16 + g * 4 + r];
        #pragma unroll
        for (int rs = 0; rs < 4; ++rs) {
            const size_t row = n0 + rs * 16 + nl;
            #pragma unroll
            for (int r = 0; r < 4; ++r)
                hbuf[row * KDIM + w * 64 + ct * 16 + g * 4 + r] = acc[ct][rs][r] + bv[r];
        }
    }
}

// ---------------- fallback f32 gemm ----------------
__global__ __launch_bounds__(256, 2) void gemm_fb_kernel(const float* __restrict__ x,
                                                         const float* __restrict__ W,
                                                         const float* __restrict__ bvec,
                                                         float* __restrict__ hbuf) {
    const int t  = threadIdx.x;
    const int cg = t & 15;
    const int rg = t >> 4;
    const size_t n0 = (size_t)blockIdx.x * G_ROWS;
    const int c0 = cg * 16;

    float acc[2][16];
    #pragma unroll
    for (int j = 0; j < 2; ++j)
        #pragma unroll
        for (int cc = 0; cc < 16; ++cc) acc[j][cc] = 0.f;

    for (int k4 = 0; k4 < INDIM / 4; ++k4) {
        const int k = k4 * 4;
        f32x4 xv[2];
        #pragma unroll
        for (int j = 0; j < 2; ++j)
            xv[j] = *(const f32x4*)(x + (n0 + rg + 16 * j) * INDIM + k);
        f32x4 wv[4][4];
        #pragma unroll
        for (int kk = 0; kk < 4; ++kk)
            #pragma unroll
            for (int q = 0; q < 4; ++q)
                wv[kk][q] = *(const f32x4*)(W + (size_t)(k + kk) * KDIM + c0 + 4 * q);
        #pragma unroll
        for (int j = 0; j < 2; ++j)
            #pragma unroll
            for (int kk = 0; kk < 4; ++kk) {
                const float xs = xv[j][kk];
                #pragma unroll
                for (int q = 0; q < 4; ++q)
                    #pragma unroll
                    for (int e = 0; e < 4; ++e)
                        acc[j][4*q+e] = fmaf(xs, wv[kk][q][e], acc[j][4*q+e]);
            }
    }
    #pragma unroll
    for (int j = 0; j < 2; ++j) {
        float* dst = hbuf + (n0 + rg + 16 * j) * KDIM + c0;
        #pragma unroll
        for (int q = 0; q < 4; ++q) {
            f32x4 v;
            #pragma unroll
            for (int e = 0; e < 4; ++e) v[e] = acc[j][4*q+e] + bvec[c0 + 4*q + e];
            *(f32x4*)(dst + 4*q) = v;
        }
    }
}

// ---------------- prep: cnorm + optional bf16 hi/lo split of cb ----------------
__global__ __launch_bounds__(256) void prep_kernel(const float* __restrict__ cb,
                                                   float* __restrict__ cnorm,
                                                   unsigned short* __restrict__ cb_hi,
                                                   unsigned short* __restrict__ cb_lo,
                                                   int do_split) {
    const int c    = blockIdx.x * 4 + (threadIdx.x >> 6);
    const int lane = threadIdx.x & 63;
    f32x4 v = ((const f32x4*)(cb + (size_t)c * KDIM))[lane];
    if (do_split) {
        u16x4 h4, l4;
        #pragma unroll
        for (int j = 0; j < 4; ++j) {
            unsigned short h = f2bf(v[j]);
            h4[j] = h;
            l4[j] = f2bf(v[j] - bf2f(h));
        }
        *(u16x4*)(cb_hi + (size_t)c * KDIM + lane * 4) = h4;
        *(u16x4*)(cb_lo + (size_t)c * KDIM + lane * 4) = l4;
    }
    float s = v[0]*v[0] + v[1]*v[1] + v[2]*v[2] + v[3]*v[3];
    #pragma unroll
    for (int off = 1; off < 64; off <<= 1) s += __shfl_xor(s, off);
    if (lane == 0) cnorm[c] = s;
}

// ---------------- vq: MFMA distances + top-2 + exact refine + gather ----------------
// LDS layout (per buffer): hi[t2][s][lane16B] at +0, lo at +16384 -> all accesses lane-linear.
template<int PRE>
__global__ __launch_bounds__(256) void vq_kernel(
    float* __restrict__ hbuf,
    const float* __restrict__ cb,
    const float* __restrict__ cnorm,
    const unsigned short* __restrict__ cb_hi,
    const unsigned short* __restrict__ cb_lo,
    float* __restrict__ idx_out)
{
    __shared__ __align__(16) char lds[2 * VBUF];

    const int t  = threadIdx.x;
    const int w  = t >> 6;
    const int l  = t & 63;
    const int nl = l & 15;
    const int g  = l >> 4;
    const int lb = l * 16;
    const size_t n0 = (size_t)blockIdx.x * V_ROWS;
    const int row = w * 16 + nl;
    float* hrow = hbuf + (n0 + row) * KDIM;

    // h fragments (hi + residual bf16) in registers
    u16x8 bhi[8], bmid[8];
    #pragma unroll
    for (int s = 0; s < 8; ++s) {
        f32x4 a = *(const f32x4*)(hrow + s * 32 + g * 8);
        f32x4 b = *(const f32x4*)(hrow + s * 32 + g * 8 + 4);
        u16x8 uh, um;
        #pragma unroll
        for (int jj = 0; jj < 4; ++jj) {
            unsigned short h0 = f2bf(a[jj]); uh[jj]   = h0; um[jj]   = f2bf(a[jj] - bf2f(h0));
            unsigned short h1 = f2bf(b[jj]); uh[4+jj] = h1; um[4+jj] = f2bf(b[jj] - bf2f(h1));
        }
        bhi[s] = uh; bmid[s] = um;
    }

    float v1 = 3.4e38f, v2 = 3.4e38f;
    int   i1 = 0, i2 = 0;

    // staging: thread covers (t2 in 0..1) x (s_stage = w*2+sv, sv in 0..1), fragment (g, nl)
    u16x8 rh[2][2], rl[2][2];

    #pragma unroll
    for (int t2 = 0; t2 < 2; ++t2)
        #pragma unroll
        for (int sv = 0; sv < 2; ++sv) {
            const int sst = w * 2 + sv;
            if (PRE) {
                const size_t off = (size_t)(t2 * 16 + nl) * KDIM + (sst * 4 + g) * 8;
                rh[t2][sv] = *(const u16x8*)(cb_hi + off);
                rl[t2][sv] = *(const u16x8*)(cb_lo + off);
            } else {
                const float* p = cb + (size_t)(t2 * 16 + nl) * KDIM + (sst * 4 + g) * 8;
                f32x4 a = *(const f32x4*)(p);
                f32x4 b = *(const f32x4*)(p + 4);
                u16x8 uh, ul;
                #pragma unroll
                for (int jj = 0; jj < 4; ++jj) {
                    unsigned short h0 = f2bf(a[jj]); uh[jj]   = h0; ul[jj]   = f2bf(a[jj] - bf2f(h0));
                    unsigned short h1 = f2bf(b[jj]); uh[4+jj] = h1; ul[4+jj] = f2bf(b[jj] - bf2f(h1));
                }
                rh[t2][sv] = uh; rl[t2][sv] = ul;
            }
        }
    #pragma unroll
    for (int t2 = 0; t2 < 2; ++t2)
        #pragma unroll
        for (int sv = 0; sv < 2; ++sv) {
            const int base = (t2 * 8 + w * 2 + sv) * 1024 + lb;
            *(u16x8*)(lds + base) = rh[t2][sv];
            *(u16x8*)(lds + 16384 + base) = rl[t2][sv];
        }
    __syncthreads();

    for (int S = 0; S < NSTEP; ++S) {
        const int b = S & 1;
        // prefetch next step's codes into regs
        if (S + 1 < NSTEP) {
            #pragma unroll
            for (int t2 = 0; t2 < 2; ++t2)
                #pragma unroll
                for (int sv = 0; sv < 2; ++sv) {
                    const int sst = w * 2 + sv;
                    const int code = (S + 1) * 32 + t2 * 16 + nl;
                    if (PRE) {
                        const size_t off = (size_t)code * KDIM + (sst * 4 + g) * 8;
                        rh[t2][sv] = *(const u16x8*)(cb_hi + off);
                        rl[t2][sv] = *(const u16x8*)(cb_lo + off);
                    } else {
                        const float* p = cb + (size_t)code * KDIM + (sst * 4 + g) * 8;
                        f32x4 a = *(const f32x4*)(p);
                        f32x4 bb = *(const f32x4*)(p + 4);
                        u16x8 uh, ul;
                        #pragma unroll
                        for (int jj = 0; jj < 4; ++jj) {
                            unsigned short h0 = f2bf(a[jj]);  uh[jj]   = h0; ul[jj]   = f2bf(a[jj] - bf2f(h0));
                            unsigned short h1 = f2bf(bb[jj]); uh[4+jj] = h1; ul[4+jj] = f2bf(bb[jj] - bf2f(h1));
                        }
                        rh[t2][sv] = uh; rl[t2][sv] = ul;
                    }
                }
        }
        // cn for this step's codes (global; tiny, cache-resident)
        f32x4 cn0 = *(const f32x4*)(cnorm + S * 32 + g * 4);
        f32x4 cn1 = *(const f32x4*)(cnorm + S * 32 + 16 + g * 4);
        // compute from buffer b (lane-linear reads)
        {
            const char* buf = lds + b * VBUF;
            #pragma unroll
            for (int t2 = 0; t2 < 2; ++t2) {
                f32x4 acc = {0.f, 0.f, 0.f, 0.f};
                #pragma unroll
                for (int s = 0; s < 8; ++s) {
                    const int base = (t2 * 8 + s) * 1024 + lb;
                    u16x8 ahi = *(const u16x8*)(buf + base);
                    u16x8 alo = *(const u16x8*)(buf + 16384 + base);
                    acc = mfma16(ahi, bhi[s],  acc);
                    acc = mfma16(ahi, bmid[s], acc);
                    acc = mfma16(alo, bhi[s],  acc);
                }
                const f32x4 cn = t2 ? cn1 : cn0;
                #pragma unroll
                for (int r = 0; r < 4; ++r) {
                    const float d2 = cn[r] - 2.0f * acc[r];
                    const int c = S * 32 + t2 * 16 + g * 4 + r;
                    if (d2 < v1)      { v2 = v1; i2 = i1; v1 = d2; i1 = c; }
                    else if (d2 < v2) { v2 = d2; i2 = c; }
                }
            }
        }
        __syncthreads();                        // all waves done reading buffer b
        if (S + 1 < NSTEP) {
            char* nbuf = lds + (b ^ 1) * VBUF;
            #pragma unroll
            for (int t2 = 0; t2 < 2; ++t2)
                #pragma unroll
                for (int sv = 0; sv < 2; ++sv) {
                    const int base = (t2 * 8 + w * 2 + sv) * 1024 + lb;
                    *(u16x8*)(nbuf + base) = rh[t2][sv];
                    *(u16x8*)(nbuf + 16384 + base) = rl[t2][sv];
                }
        }
        __syncthreads();                        // next buffer ready
    }

    // merge top-2 across the 4 k-lane-groups (disjoint code sets per g)
    #pragma unroll
    for (int off = 16; off <= 32; off <<= 1) {
        float ov1 = __shfl_xor(v1, off); int oi1 = __shfl_xor(i1, off);
        float ov2 = __shfl_xor(v2, off); int oi2 = __shfl_xor(i2, off);
        if (ov1 < v1 || (ov1 == v1 && oi1 < i1)) {
            float tv = v1; int ti = i1; v1 = ov1; i1 = oi1; ov1 = tv; oi1 = ti;
            tv = v2; ti = i2; v2 = ov2; i2 = oi2; ov2 = tv; oi2 = ti;
        }
        if (ov1 < v2 || (ov1 == v2 && oi1 < i2)) { v2 = ov1; i2 = oi1; }
    }

    // defensive clamp
    i1 = (i1 < 0) ? 0 : (i1 > NCODES - 1 ? NCODES - 1 : i1);
    i2 = (i2 < 0) ? 0 : (i2 > NCODES - 1 ? NCODES - 1 : i2);

    // exact f32 refine of both candidates
    const float* cp1 = cb + (size_t)i1 * KDIM;
    const float* cp2 = cb + (size_t)i2 * KDIM;
    float da = 0.f, db = 0.f;
    #pragma unroll
    for (int s = 0; s < 8; ++s) {
        f32x4 h0 = *(const f32x4*)(hrow + s * 32 + g * 8);
        f32x4 h1 = *(const f32x4*)(hrow + s * 32 + g * 8 + 4);
        f32x4 a1 = *(const f32x4*)(cp1 + s * 32 + g * 8);
        f32x4 b1 = *(const f32x4*)(cp1 + s * 32 + g * 8 + 4);
        f32x4 a2 = *(const f32x4*)(cp2 + s * 32 + g * 8);
        f32x4 b2 = *(const f32x4*)(cp2 + s * 32 + g * 8 + 4);
        #pragma unroll
        for (int jj = 0; jj < 4; ++jj) {
            da = fmaf(a1[jj], h0[jj], da); da = fmaf(b1[jj], h1[jj], da);
            db = fmaf(a2[jj], h0[jj], db); db = fmaf(b2[jj], h1[jj], db);
        }
    }
    da += __shfl_xor(da, 16); da += __shfl_xor(da, 32);
    db += __shfl_xor(db, 16); db += __shfl_xor(db, 32);
    const float d2a = cnorm[i1] - 2.f * da;
    const float d2b = cnorm[i2] - 2.f * db;
    const int win = (d2a < d2b || (d2a == d2b && i1 < i2)) ? i1 : i2;

    // gather codes (overwrite h row) + write idx
    const float* cw = cb + (size_t)win * KDIM;
    #pragma unroll
    for (int s = 0; s < 8; ++s) {
        *(f32x4*)(hrow + s * 32 + g * 8)     = *(const f32x4*)(cw + s * 32 + g * 8);
        *(f32x4*)(hrow + s * 32 + g * 8 + 4) = *(const f32x4*)(cw + s * 32 + g * 8 + 4);
    }
    if (g == 0) idx_out[n0 + row] = (float)win;
}

extern "C" void kernel_launch(void* const* d_in, const int* in_sizes, int n_in,
                              void* d_out, int out_size, void* d_ws, size_t ws_size,
                              hipStream_t stream) {
    (void)in_sizes; (void)n_in; (void)out_size;
    const float* x    = (const float*)d_in[0];
    const float* W    = (const float*)d_in[1];
    const float* bvec = (const float*)d_in[2];
    const float* cb   = (const float*)d_in[3];

    float* codes_out = (float*)d_out;                       // doubles as h buffer
    float* idx_out   = (float*)d_out + (size_t)NROWS * KDIM;

    // ws layout: cnorm[16KB] | cb_hi[2MB] | cb_lo[2MB] | wt_hi/md/lo[3x0.5MB]
    float* cnorm = (float*)d_ws;
    unsigned short* cb_hi = (unsigned short*)((char*)d_ws + 16384);
    unsigned short* cb_lo = cb_hi + (size_t)NCODES * KDIM;
    unsigned short* wt_hi = cb_lo + (size_t)NCODES * KDIM;
    unsigned short* wt_md = wt_hi + (size_t)INDIM * KDIM;
    unsigned short* wt_lo = wt_md + (size_t)INDIM * KDIM;

    const size_t need_cb   = 16384 + (size_t)NCODES * KDIM * 2 * sizeof(unsigned short);
    const size_t need_full = need_cb + (size_t)INDIM * KDIM * 3 * sizeof(unsigned short);

    const int pre_cb = (ws_size >= need_cb) ? 1 : 0;
    const int fast_g = (ws_size >= need_full) ? 1 : 0;

    if (fast_g) {
        wprep_kernel<<<INDIM / 4, 256, 0, stream>>>(W, wt_hi, wt_md, wt_lo);
        gemm_mfma_kernel<<<NROWS / MG_ROWS, 256, 0, stream>>>(x, wt_hi, wt_md, wt_lo, bvec, codes_out);
    } else {
        gemm_fb_kernel<<<NROWS / G_ROWS, 256, 0, stream>>>(x, W, bvec, codes_out);
    }
    prep_kernel<<<NCODES / 4, 256, 0, stream>>>(cb, cnorm, cb_hi, cb_lo, pre_cb);
    if (pre_cb)
        vq_kernel<1><<<NROWS / V_ROWS, 256, 0, stream>>>(codes_out, cb, cnorm, cb_hi, cb_lo, idx_out);
    else
        vq_kernel<0><<<NROWS / V_ROWS, 256, 0, stream>>>(codes_out, cb, cnorm, cb_hi, cb_lo, idx_out);
}